// Round 5
// baseline (129.988 us; speedup 1.0000x reference)
//
#include <hip/hip_runtime.h>
#include <math.h>

#define NBATCH 8
#define SEQL   2048
#define NHEAD  16
#define DDIM   64
#define CHK    128
#define NCHUNK (SEQL / CHK)
#define MH     32
#define NTHREADS 1024
#define EPSV   1e-6f
#define QSTR   72      // sQ/sK row stride (ushort): 144B, 16B-aligned
#define TSTR   132     // sKt/sVt row stride: 264B, 8B-aligned
#define SSTR   68      // sSt row stride: 136B, 8B-aligned

typedef float  f32x16 __attribute__((ext_vector_type(16)));
typedef float  f32x4v __attribute__((ext_vector_type(4)));
typedef short  bf16x8 __attribute__((ext_vector_type(8)));

#define MFMA32(a,b,c) __builtin_amdgcn_mfma_f32_32x32x16_bf16((a),(b),(c),0,0,0)

__device__ __forceinline__ float phi(float x) { return x > 0.0f ? x + 1.0f : __expf(x); }

__device__ __forceinline__ unsigned int cvt_pk(float lo, float hi) {
    unsigned int r;
    asm("v_cvt_pk_bf16_f32 %0, %1, %2" : "=v"(r) : "v"(lo), "v"(hi));
    return r;
}
__device__ __forceinline__ ushort f2bf(float x) {
    union { float f; unsigned int i; } t; t.f = x;
    unsigned int r = t.i + 0x7fffu + ((t.i >> 16) & 1u);
    return (ushort)(r >> 16);
}
__device__ __forceinline__ float bf2f(short u) {
    union { unsigned int i; float f; } t;
    t.i = ((unsigned int)(unsigned short)u) << 16;
    return t.f;
}
__device__ __forceinline__ bf16x8 ld16B(const ushort* p) { return *reinterpret_cast<const bf16x8*>(p); }
__device__ __forceinline__ bf16x8 ld8B(const ushort* p) {
    union { bf16x8 v; uint2 u[2]; } x;
    x.u[0] = *(const uint2*)p;
    x.u[1] = *(const uint2*)(p + 4);
    return x.v;
}
__device__ __forceinline__ void pl32swap(unsigned int &a, unsigned int &b) {
    asm volatile("v_permlane32_swap_b32 %0, %1" : "+v"(a), "+v"(b));
}
__device__ __forceinline__ float halfswap_add(float x) {
    unsigned int a = __float_as_uint(x), b = a;
    pl32swap(a, b);                // a = lo-half both; b = hi-half both
    return __uint_as_float(a) + __uint_as_float(b);
}
// P^T D-regs (s=crow(r,hi), t=l&31) -> PV A-fragment (row t=l&31, k=8*hi+j)
__device__ __forceinline__ bf16x8 make_pa(float p0,float p1,float p2,float p3,
                                          float p4,float p5,float p6,float p7) {
    unsigned int a0 = cvt_pk(p0,p1), b0 = cvt_pk(p4,p5);
    unsigned int a1 = cvt_pk(p2,p3), b1 = cvt_pk(p6,p7);
    pl32swap(a0,b0); pl32swap(a1,b1);
    union { bf16x8 v; unsigned int u[4]; } x;
    x.u[0]=a0; x.u[1]=a1; x.u[2]=b0; x.u[3]=b1;
    return x.v;
}

__global__ __launch_bounds__(NTHREADS)
void linattn_mfma4(const float* __restrict__ qg, const float* __restrict__ kg,
                   const float* __restrict__ vg, float* __restrict__ og) {
    __shared__ __align__(16) ushort sQ[CHK][QSTR];     // phi(Q) [t][d]
    __shared__ __align__(16) ushort sK[CHK][QSTR];     // phi(K) [s][d]
    __shared__ __align__(16) ushort sKt[DDIM][TSTR];   // phi(K)^T [d][s]
    __shared__ __align__(16) ushort sVt[MH][TSTR];     // V^T [m][s]
    __shared__ __align__(16) ushort sSt[2][MH][SSTR];  // S^T snapshot halves [m][d]
    __shared__ __align__(16) float  sOp[6][8][CHK];    // PV partial dumps (lane-private)
    __shared__ float sZp[6][32];                       // partial rowsums
    __shared__ float sZt[CHK];                         // final z per row
    __shared__ float sKsW[2][16][64];                  // per-wave k colsum partials
    __shared__ float sKS[64];                          // running ksum (prev chunks)
    __shared__ __align__(16) ushort sKSbf[64];

    const int tid = threadIdx.x;
    const int w   = tid >> 6;
    const int l   = tid & 63;
    const int l31 = l & 31;
    const int hi  = l >> 5;

    const int bid   = blockIdx.x;
    const int nh    = bid & 127;       // b, b+128 share (n,h) -> same XCD slot
    const int mhalf = bid >> 7;
    const int n  = nh >> 4;
    const int hh = nh & 15;

    const size_t base0 = ((size_t)n * SEQL * NHEAD + hh) * DDIM;
    const float* qb = qg + base0;
    const float* kb = kg + base0;
    const float* vb = vg + base0 + (size_t)mhalf * MH;
    float*       ob = og + base0 + (size_t)mhalf * MH;

    // role decode: waves 0-3 diag strips, 4-9 off-diag tiles, 10-13 state, 14 ksum
    const int pidx = w - 4;
    const int pc = (pidx < 1) ? 1 : (pidx < 3) ? 2 : 3;
    const int pg = pidx - ((pc == 1) ? 0 : (pc == 2) ? 1 : 3);
    const int dt = (w - 10) >> 1;
    const int kh = (w - 10) & 1;

    // staging geometry: Q/K row-pairs (all waves), V s-pairs (waves 8-15)
    const int r2 = tid >> 4;            // 0..63
    const int x4 = (tid & 15) << 2;
    const int tv  = tid - 512;
    const int sp2 = (tv >> 3) << 1;
    const int vm4 = (tv & 7) << 2;

    float4 qrA, qrB, krA, krB, vrA, vrB;
    qrA = *(const float4*)(qb + (size_t)(2*r2    ) * 1024 + x4);
    qrB = *(const float4*)(qb + (size_t)(2*r2 + 1) * 1024 + x4);
    krA = *(const float4*)(kb + (size_t)(2*r2    ) * 1024 + x4);
    krB = *(const float4*)(kb + (size_t)(2*r2 + 1) * 1024 + x4);
    if (w >= 8) {
        vrA = *(const float4*)(vb + (size_t)(sp2    ) * 1024 + vm4);
        vrB = *(const float4*)(vb + (size_t)(sp2 + 1) * 1024 + vm4);
    }

    if (w == 14) sKS[l] = 0.0f;

    f32x16 accS;
    #pragma unroll
    for (int i = 0; i < 16; ++i) accS[i] = 0.0f;

    for (int tc = 0; tc < NCHUNK; ++tc) {
        const int t0 = tc * CHK;
        const int cur = tc & 1, prv = cur ^ 1;

        // ================= phase A: ksum commit + stage =================
        if (w == 14) {
            float s = sKS[l];
            if (tc > 0) {
                #pragma unroll
                for (int ww = 0; ww < 16; ++ww) s += sKsW[prv][ww][l];
                sKS[l] = s;
            }
            sKSbf[l] = f2bf(s);
        }
        {
            const float q0x=phi(qrA.x), q0y=phi(qrA.y), q0z=phi(qrA.z), q0w=phi(qrA.w);
            const float q1x=phi(qrB.x), q1y=phi(qrB.y), q1z=phi(qrB.z), q1w=phi(qrB.w);
            uint2 u;
            u.x = cvt_pk(q0x,q0y); u.y = cvt_pk(q0z,q0w);
            *(uint2*)&sQ[2*r2][x4] = u;
            u.x = cvt_pk(q1x,q1y); u.y = cvt_pk(q1z,q1w);
            *(uint2*)&sQ[2*r2+1][x4] = u;

            const float k0x=phi(krA.x), k0y=phi(krA.y), k0z=phi(krA.z), k0w=phi(krA.w);
            const float k1x=phi(krB.x), k1y=phi(krB.y), k1z=phi(krB.z), k1w=phi(krB.w);
            u.x = cvt_pk(k0x,k0y); u.y = cvt_pk(k0z,k0w);
            *(uint2*)&sK[2*r2][x4] = u;
            u.x = cvt_pk(k1x,k1y); u.y = cvt_pk(k1z,k1w);
            *(uint2*)&sK[2*r2+1][x4] = u;

            *(unsigned int*)&sKt[x4+0][2*r2] = cvt_pk(k0x, k1x);
            *(unsigned int*)&sKt[x4+1][2*r2] = cvt_pk(k0y, k1y);
            *(unsigned int*)&sKt[x4+2][2*r2] = cvt_pk(k0z, k1z);
            *(unsigned int*)&sKt[x4+3][2*r2] = cvt_pk(k0w, k1w);

            float kp0 = k0x + k1x, kp1 = k0y + k1y, kp2 = k0z + k1z, kp3 = k0w + k1w;
            kp0 += __shfl_xor(kp0, 16); kp0 += __shfl_xor(kp0, 32);
            kp1 += __shfl_xor(kp1, 16); kp1 += __shfl_xor(kp1, 32);
            kp2 += __shfl_xor(kp2, 16); kp2 += __shfl_xor(kp2, 32);
            kp3 += __shfl_xor(kp3, 16); kp3 += __shfl_xor(kp3, 32);
            if (l < 16) {
                float4 kp = {kp0, kp1, kp2, kp3};
                *(float4*)&sKsW[cur][w][4*l] = kp;
            }
        }
        if (w >= 8) {
            *(unsigned int*)&sVt[vm4+0][sp2] = cvt_pk(vrA.x, vrB.x);
            *(unsigned int*)&sVt[vm4+1][sp2] = cvt_pk(vrA.y, vrB.y);
            *(unsigned int*)&sVt[vm4+2][sp2] = cvt_pk(vrA.z, vrB.z);
            *(unsigned int*)&sVt[vm4+3][sp2] = cvt_pk(vrA.w, vrB.w);
        }
        if (w >= 10 && w < 14) {   // snapshot S^T (this wave's (dt,kh) tile)
            ushort* st = &sSt[kh][l31][32*dt];
            #pragma unroll
            for (int rg = 0; rg < 4; ++rg) {
                uint2 s2;
                s2.x = cvt_pk(accS[4*rg+0], accS[4*rg+1]);
                s2.y = cvt_pk(accS[4*rg+2], accS[4*rg+3]);
                *(uint2*)(st + 8*rg + 4*hi) = s2;
            }
        }
        __syncthreads();   // bar1

        // ================= phase B: prefetch + all matmuls =================
        if (tc + 1 < NCHUNK) {
            const int t1 = t0 + CHK;
            qrA = *(const float4*)(qb + (size_t)(t1 + 2*r2    ) * 1024 + x4);
            qrB = *(const float4*)(qb + (size_t)(t1 + 2*r2 + 1) * 1024 + x4);
            krA = *(const float4*)(kb + (size_t)(t1 + 2*r2    ) * 1024 + x4);
            krB = *(const float4*)(kb + (size_t)(t1 + 2*r2 + 1) * 1024 + x4);
            if (w >= 8) {
                vrA = *(const float4*)(vb + (size_t)(t1 + sp2    ) * 1024 + vm4);
                vrB = *(const float4*)(vb + (size_t)(t1 + sp2 + 1) * 1024 + vm4);
            }
        }

        f32x16 accO;
        float zl = 0.0f;

        if (w < 4) {
            // -------- diagonal strip c=w: QK^T(c,c) + PV + QS + qz --------
            const int c = w;
            const bf16x8 aQ0 = ld16B(&sQ[32*c + l31][ 0 + 8*hi]);
            const bf16x8 aQ1 = ld16B(&sQ[32*c + l31][16 + 8*hi]);
            const bf16x8 aQ2 = ld16B(&sQ[32*c + l31][32 + 8*hi]);
            const bf16x8 aQ3 = ld16B(&sQ[32*c + l31][48 + 8*hi]);

            f32x16 accP;
            #pragma unroll
            for (int i = 0; i < 16; ++i) accP[i] = 0.0f;
            accP = MFMA32(ld16B(&sK[32*c + l31][ 0 + 8*hi]), aQ0, accP);
            accP = MFMA32(ld16B(&sK[32*c + l31][16 + 8*hi]), aQ1, accP);
            accP = MFMA32(ld16B(&sK[32*c + l31][32 + 8*hi]), aQ2, accP);
            accP = MFMA32(ld16B(&sK[32*c + l31][48 + 8*hi]), aQ3, accP);
            // causal mask (s<=t) + rowsum, all in D-registers
            float rs = 0.0f;
            #pragma unroll
            for (int r = 0; r < 16; ++r) {
                const int srow = (r & 3) + 8 * (r >> 2) + 4 * hi;
                const float pv = (srow <= l31) ? accP[r] : 0.0f;
                accP[r] = pv;
                rs += pv;
            }
            const bf16x8 pa0 = make_pa(accP[0],accP[1],accP[2],accP[3],
                                       accP[4],accP[5],accP[6],accP[7]);
            const bf16x8 pa1 = make_pa(accP[8],accP[9],accP[10],accP[11],
                                       accP[12],accP[13],accP[14],accP[15]);
            #pragma unroll
            for (int i = 0; i < 16; ++i) accO[i] = 0.0f;
            accO = MFMA32(pa0, ld8B(&sVt[l31][32*c +  0 + 8*hi]), accO);
            accO = MFMA32(pa1, ld8B(&sVt[l31][32*c + 16 + 8*hi]), accO);
            #pragma unroll
            for (int buf = 0; buf < 2; ++buf) {
                accO = MFMA32(aQ0, ld8B(&sSt[buf][l31][ 0 + 8*hi]), accO);
                accO = MFMA32(aQ1, ld8B(&sSt[buf][l31][16 + 8*hi]), accO);
                accO = MFMA32(aQ2, ld8B(&sSt[buf][l31][32 + 8*hi]), accO);
                accO = MFMA32(aQ3, ld8B(&sSt[buf][l31][48 + 8*hi]), accO);
            }
            // qz = q_t . ksum_prev (VALU dot over this lane's d-half)
            float qz = 0.0f;
            {
                const bf16x8 ks0 = ld16B(&sKSbf[ 0 + 8*hi]);
                const bf16x8 ks1 = ld16B(&sKSbf[16 + 8*hi]);
                const bf16x8 ks2 = ld16B(&sKSbf[32 + 8*hi]);
                const bf16x8 ks3 = ld16B(&sKSbf[48 + 8*hi]);
                #pragma unroll
                for (int j = 0; j < 8; ++j) {
                    qz += bf2f(aQ0[j]) * bf2f(ks0[j]);
                    qz += bf2f(aQ1[j]) * bf2f(ks1[j]);
                    qz += bf2f(aQ2[j]) * bf2f(ks2[j]);
                    qz += bf2f(aQ3[j]) * bf2f(ks3[j]);
                }
            }
            zl = halfswap_add(rs + qz);
        } else if (w < 10) {
            // -------- off-diagonal tile (pg,pc): P^T + partial PV --------
            f32x16 accP;
            #pragma unroll
            for (int i = 0; i < 16; ++i) accP[i] = 0.0f;
            #pragma unroll
            for (int kk = 0; kk < 4; ++kk)
                accP = MFMA32(ld16B(&sK[32*pg + l31][16*kk + 8*hi]),
                              ld16B(&sQ[32*pc + l31][16*kk + 8*hi]), accP);
            float rs = 0.0f;
            #pragma unroll
            for (int r = 0; r < 16; ++r) rs += accP[r];
            const float zp = halfswap_add(rs);
            if (hi == 0) sZp[pidx][l31] = zp;
            const bf16x8 pa0 = make_pa(accP[0],accP[1],accP[2],accP[3],
                                       accP[4],accP[5],accP[6],accP[7]);
            const bf16x8 pa1 = make_pa(accP[8],accP[9],accP[10],accP[11],
                                       accP[12],accP[13],accP[14],accP[15]);
            f32x16 po;
            #pragma unroll
            for (int i = 0; i < 16; ++i) po[i] = 0.0f;
            po = MFMA32(pa0, ld8B(&sVt[l31][32*pg +  0 + 8*hi]), po);
            po = MFMA32(pa1, ld8B(&sVt[l31][32*pg + 16 + 8*hi]), po);
            #pragma unroll
            for (int rp = 0; rp < 8; ++rp) {
                float2 t; t.x = po[2*rp]; t.y = po[2*rp+1];
                *(float2*)&sOp[pidx][rp][2*l] = t;
            }
        } else if (w < 14) {
            // -------- state: S(dt) += K^T V over s-half kh --------
            #pragma unroll
            for (int kk = 0; kk < 4; ++kk) {
                const bf16x8 aK = ld8B(&sKt[32*dt + l31][64*kh + 16*kk + 8*hi]);
                const bf16x8 bV = ld8B(&sVt[l31][64*kh + 16*kk + 8*hi]);
                accS = MFMA32(aK, bV, accS);
            }
        }
        __syncthreads();   // bar2

        // ================= phase C: merge + normalize + store =================
        if (w < 4) {
            const int c = w;
            const int p0 = (c == 1) ? 0 : (c == 2) ? 1 : 3;
            for (int i = 0; i < c; ++i) {
                const int pp = p0 + i;
                #pragma unroll
                for (int rp = 0; rp < 8; ++rp) {
                    const float2 t = *(const float2*)&sOp[pp][rp][2*l];
                    accO[2*rp]     += t.x;
                    accO[2*rp + 1] += t.y;
                }
                zl += sZp[pp][l31];
            }
            zl += EPSV;
            if (hi == 0) sZt[32*c + l31] = zl;
            asm volatile("s_waitcnt lgkmcnt(0)" ::: "memory");
            __builtin_amdgcn_sched_barrier(0);
            #pragma unroll
            for (int rg = 0; rg < 4; ++rg) {
                const f32x4v z4 = *(const f32x4v*)&sZt[32*c + 8*rg + 4*hi];
                #pragma unroll
                for (int rr = 0; rr < 4; ++rr) {
                    const int row = t0 + 32*c + rr + 8*rg + 4*hi;
                    ob[(size_t)row * 1024 + l31] =
                        accO[4*rg + rr] * __builtin_amdgcn_rcpf(z4[rr]);
                }
            }
        }
    }
}

extern "C" void kernel_launch(void* const* d_in, const int* in_sizes, int n_in,
                              void* d_out, int out_size, void* d_ws, size_t ws_size,
                              hipStream_t stream) {
    const float* q = (const float*)d_in[0];
    const float* k = (const float*)d_in[1];
    const float* v = (const float*)d_in[2];
    float* o = (float*)d_out;
    dim3 grid(NBATCH * NHEAD * 2);   // 128 (n,h) x 2 m-halves = 256 blocks (1/CU)
    linattn_mfma4<<<grid, NTHREADS, 0, stream>>>(q, k, v, o);
}

// Round 7
// 123.844 us; speedup vs baseline: 1.0496x; 1.0496x over previous
//
#include <hip/hip_runtime.h>
#include <math.h>

#define NBATCH 8
#define SEQL   2048
#define NHEAD  16
#define DDIM   64
#define CHK    128
#define NCHUNK (SEQL / CHK)
#define MH     32
#define NTHREADS 1024
#define EPSV   1e-6f
#define QSTR   72      // sQ/sK row stride (ushort): 144B, 16B-aligned
#define TSTR   132     // sKt/sVt row stride: 264B, 8B-aligned
#define SSTR   68      // sSt row stride: 136B, 8B-aligned

typedef float  f32x16 __attribute__((ext_vector_type(16)));
typedef float  f32x4v __attribute__((ext_vector_type(4)));
typedef short  bf16x8 __attribute__((ext_vector_type(8)));

#define MFMA32(a,b,c) __builtin_amdgcn_mfma_f32_32x32x16_bf16((a),(b),(c),0,0,0)

__device__ __forceinline__ float phi(float x) { return x > 0.0f ? x + 1.0f : __expf(x); }

__device__ __forceinline__ unsigned int cvt_pk(float lo, float hi) {
    unsigned int r;
    asm("v_cvt_pk_bf16_f32 %0, %1, %2" : "=v"(r) : "v"(lo), "v"(hi));
    return r;
}
__device__ __forceinline__ ushort f2bf(float x) {
    union { float f; unsigned int i; } t; t.f = x;
    unsigned int r = t.i + 0x7fffu + ((t.i >> 16) & 1u);
    return (ushort)(r >> 16);
}
__device__ __forceinline__ float bf2f(short u) {
    union { unsigned int i; float f; } t;
    t.i = ((unsigned int)(unsigned short)u) << 16;
    return t.f;
}
__device__ __forceinline__ bf16x8 ld16B(const ushort* p) { return *reinterpret_cast<const bf16x8*>(p); }
__device__ __forceinline__ bf16x8 ld8B(const ushort* p) {
    union { bf16x8 v; uint2 u[2]; } x;
    x.u[0] = *(const uint2*)p;
    x.u[1] = *(const uint2*)(p + 4);
    return x.v;
}
__device__ __forceinline__ void pl32swap(unsigned int &a, unsigned int &b) {
    asm volatile("v_permlane32_swap_b32 %0, %1" : "+v"(a), "+v"(b));
}
__device__ __forceinline__ float halfswap_add(float x) {
    unsigned int a = __float_as_uint(x), b = a;
    pl32swap(a, b);
    return __uint_as_float(a) + __uint_as_float(b);
}
// P^T D-regs (s=crow(r,hi), t=l&31) -> PV A-fragment (row t, k slice). Verified R5.
__device__ __forceinline__ bf16x8 make_pa(float p0,float p1,float p2,float p3,
                                          float p4,float p5,float p6,float p7) {
    unsigned int a0 = cvt_pk(p0,p1), b0 = cvt_pk(p4,p5);
    unsigned int a1 = cvt_pk(p2,p3), b1 = cvt_pk(p6,p7);
    pl32swap(a0,b0); pl32swap(a1,b1);
    union { bf16x8 v; unsigned int u[4]; } x;
    x.u[0]=a0; x.u[1]=a1; x.u[2]=b0; x.u[3]=b1;
    return x.v;
}

__global__ __launch_bounds__(NTHREADS)
__attribute__((amdgpu_waves_per_eu(4, 4)))
void linattn_mfma6(const float* __restrict__ qg, const float* __restrict__ kg,
                   const float* __restrict__ vg, float* __restrict__ og) {
    __shared__ __align__(16) ushort sQ[CHK][QSTR];     // phi(Q) [t][d]
    __shared__ __align__(16) ushort sK[CHK][QSTR];     // phi(K) [s][d]
    __shared__ __align__(16) ushort sKt[DDIM][TSTR];   // phi(K)^T [d][s]
    __shared__ __align__(16) ushort sVt[2][MH][TSTR];  // V^T [pp][m][s]
    __shared__ __align__(16) ushort sSt[2][MH][SSTR];  // S^T snapshot halves [kh][m][d]
    __shared__ __align__(16) float  sOp[6][8][CHK];    // off-diag PV partial dumps
    __shared__ float sZp[6][32];                       // off-diag rowsum partials
    __shared__ float sZt[CHK];                         // final z per row
    __shared__ float sKsW[2][16][64];                  // per-wave k colsum partials
    __shared__ float sKS[64];                          // running ksum (f32)
    __shared__ __align__(16) ushort sKSbf[64];         // ksum bf16 row

    const int tid = threadIdx.x;
    const int w   = tid >> 6;
    const int l   = tid & 63;
    const int l31 = l & 31;
    const int hi  = l >> 5;

    const int bid   = blockIdx.x;
    const int nh    = bid & 127;       // b, b+128 share (n,h) -> same XCD slot
    const int mhalf = bid >> 7;
    const int n  = nh >> 4;
    const int hh = nh & 15;

    const size_t base0 = ((size_t)n * SEQL * NHEAD + hh) * DDIM;
    const float* qb = qg + base0;
    const float* kb = kg + base0;
    const float* vb = vg + base0 + (size_t)mhalf * MH;
    float*       ob = og + base0 + (size_t)mhalf * MH;

    // roles: w0-3 diag strips, 4-9 off-diag tiles, 10-13 state (dt,kh), 14 ksum
    const int pidx = w - 4;
    const int pc = (pidx < 1) ? 1 : (pidx < 3) ? 2 : 3;
    const int pg = pidx - ((pc == 1) ? 0 : (pc == 2) ? 1 : 3);
    const int dt = (w - 10) >> 1;
    const int kh = (w - 10) & 1;

    // staging geometry
    const int r2 = tid >> 4;           // 0..63 -> rows 2r2, 2r2+1
    const int x4 = (tid & 15) << 2;
    const int tv  = tid - 512;
    const int sp2 = (tv >> 3) << 1;
    const int vm4 = (tv & 7) << 2;

    float4 qrA, qrB, krA, krB, vrA, vrB;
    qrA = *(const float4*)(qb + (size_t)(2*r2    ) * 1024 + x4);
    qrB = *(const float4*)(qb + (size_t)(2*r2 + 1) * 1024 + x4);
    krA = *(const float4*)(kb + (size_t)(2*r2    ) * 1024 + x4);
    krB = *(const float4*)(kb + (size_t)(2*r2 + 1) * 1024 + x4);
    if (w >= 8) {
        vrA = *(const float4*)(vb + (size_t)(sp2    ) * 1024 + vm4);
        vrB = *(const float4*)(vb + (size_t)(sp2 + 1) * 1024 + vm4);
    }

    if (w == 14) sKS[l] = 0.0f;

    f32x16 accS;
    #pragma unroll
    for (int i = 0; i < 16; ++i) accS[i] = 0.0f;

    for (int tc = 0; tc < NCHUNK; ++tc) {
        const int t0 = tc * CHK;
        const int cur = tc & 1, prv = cur ^ 1;

        // ================= phase A: ksum commit + stage =================
        if (w == 14) {
            float s = sKS[l];
            if (tc > 0) {
                #pragma unroll
                for (int ww = 0; ww < 16; ++ww) s += sKsW[prv][ww][l];
                sKS[l] = s;
            }
            sKSbf[l] = f2bf(s);
        }
        {
            const float q0x=phi(qrA.x), q0y=phi(qrA.y), q0z=phi(qrA.z), q0w=phi(qrA.w);
            const float q1x=phi(qrB.x), q1y=phi(qrB.y), q1z=phi(qrB.z), q1w=phi(qrB.w);
            uint2 u;
            u.x = cvt_pk(q0x,q0y); u.y = cvt_pk(q0z,q0w);
            *(uint2*)&sQ[2*r2][x4] = u;
            u.x = cvt_pk(q1x,q1y); u.y = cvt_pk(q1z,q1w);
            *(uint2*)&sQ[2*r2+1][x4] = u;

            const float k0x=phi(krA.x), k0y=phi(krA.y), k0z=phi(krA.z), k0w=phi(krA.w);
            const float k1x=phi(krB.x), k1y=phi(krB.y), k1z=phi(krB.z), k1w=phi(krB.w);
            u.x = cvt_pk(k0x,k0y); u.y = cvt_pk(k0z,k0w);
            *(uint2*)&sK[2*r2][x4] = u;
            u.x = cvt_pk(k1x,k1y); u.y = cvt_pk(k1z,k1w);
            *(uint2*)&sK[2*r2+1][x4] = u;

            *(unsigned int*)&sKt[x4+0][2*r2] = cvt_pk(k0x, k1x);
            *(unsigned int*)&sKt[x4+1][2*r2] = cvt_pk(k0y, k1y);
            *(unsigned int*)&sKt[x4+2][2*r2] = cvt_pk(k0z, k1z);
            *(unsigned int*)&sKt[x4+3][2*r2] = cvt_pk(k0w, k1w);

            float kp0 = k0x + k1x, kp1 = k0y + k1y, kp2 = k0z + k1z, kp3 = k0w + k1w;
            kp0 += __shfl_xor(kp0, 16); kp0 += __shfl_xor(kp0, 32);
            kp1 += __shfl_xor(kp1, 16); kp1 += __shfl_xor(kp1, 32);
            kp2 += __shfl_xor(kp2, 16); kp2 += __shfl_xor(kp2, 32);
            kp3 += __shfl_xor(kp3, 16); kp3 += __shfl_xor(kp3, 32);
            if (l < 16) {
                float4 kp = {kp0, kp1, kp2, kp3};
                *(float4*)&sKsW[cur][w][4*l] = kp;
            }
        }
        if (w >= 8) {
            *(unsigned int*)&sVt[cur][vm4+0][sp2] = cvt_pk(vrA.x, vrB.x);
            *(unsigned int*)&sVt[cur][vm4+1][sp2] = cvt_pk(vrA.y, vrB.y);
            *(unsigned int*)&sVt[cur][vm4+2][sp2] = cvt_pk(vrA.z, vrB.z);
            *(unsigned int*)&sVt[cur][vm4+3][sp2] = cvt_pk(vrA.w, vrB.w);
        }
        if (w >= 10 && w < 14) {       // snapshot S^T (this wave's (dt,kh) tile)
            ushort* st = &sSt[kh][l31][32*dt];
            #pragma unroll
            for (int rg = 0; rg < 4; ++rg) {
                uint2 s2;
                s2.x = cvt_pk(accS[4*rg+0], accS[4*rg+1]);
                s2.y = cvt_pk(accS[4*rg+2], accS[4*rg+3]);
                *(uint2*)(st + 8*rg + 4*hi) = s2;
            }
        }
        __syncthreads();   // bar1

        // ================= phase B: prefetch + all matmuls =================
        if (tc + 1 < NCHUNK) {
            const int t1 = t0 + CHK;
            qrA = *(const float4*)(qb + (size_t)(t1 + 2*r2    ) * 1024 + x4);
            qrB = *(const float4*)(qb + (size_t)(t1 + 2*r2 + 1) * 1024 + x4);
            krA = *(const float4*)(kb + (size_t)(t1 + 2*r2    ) * 1024 + x4);
            krB = *(const float4*)(kb + (size_t)(t1 + 2*r2 + 1) * 1024 + x4);
            if (w >= 8) {
                vrA = *(const float4*)(vb + (size_t)(t1 + sp2    ) * 1024 + vm4);
                vrB = *(const float4*)(vb + (size_t)(t1 + sp2 + 1) * 1024 + vm4);
            }
        }

        f32x16 accO;
        float zl = 0.0f;

        if (w < 4) {
            // -------- diagonal strip c=w: QK^T(c,c) + PV + QS + qz --------
            const int c = w;
            const bf16x8 aQ0 = ld16B(&sQ[32*c + l31][ 0 + 8*hi]);
            const bf16x8 aQ1 = ld16B(&sQ[32*c + l31][16 + 8*hi]);
            const bf16x8 aQ2 = ld16B(&sQ[32*c + l31][32 + 8*hi]);
            const bf16x8 aQ3 = ld16B(&sQ[32*c + l31][48 + 8*hi]);

            f32x16 accP;
            #pragma unroll
            for (int i = 0; i < 16; ++i) accP[i] = 0.0f;
            accP = MFMA32(ld16B(&sK[32*c + l31][ 0 + 8*hi]), aQ0, accP);
            accP = MFMA32(ld16B(&sK[32*c + l31][16 + 8*hi]), aQ1, accP);
            accP = MFMA32(ld16B(&sK[32*c + l31][32 + 8*hi]), aQ2, accP);
            accP = MFMA32(ld16B(&sK[32*c + l31][48 + 8*hi]), aQ3, accP);
            // causal mask (s<=t) + rowsum, all in D-registers
            float rs = 0.0f;
            #pragma unroll
            for (int r = 0; r < 16; ++r) {
                const int srow = (r & 3) + 8 * (r >> 2) + 4 * hi;
                const float pv = (srow <= l31) ? accP[r] : 0.0f;
                accP[r] = pv;
                rs += pv;
            }
            const bf16x8 pa0 = make_pa(accP[0],accP[1],accP[2],accP[3],
                                       accP[4],accP[5],accP[6],accP[7]);
            const bf16x8 pa1 = make_pa(accP[8],accP[9],accP[10],accP[11],
                                       accP[12],accP[13],accP[14],accP[15]);
            #pragma unroll
            for (int i = 0; i < 16; ++i) accO[i] = 0.0f;
            accO = MFMA32(pa0, ld8B(&sVt[cur][l31][32*c +  0 + 8*hi]), accO);
            accO = MFMA32(pa1, ld8B(&sVt[cur][l31][32*c + 16 + 8*hi]), accO);
            #pragma unroll
            for (int buf = 0; buf < 2; ++buf) {
                accO = MFMA32(aQ0, ld8B(&sSt[buf][l31][ 0 + 8*hi]), accO);
                accO = MFMA32(aQ1, ld8B(&sSt[buf][l31][16 + 8*hi]), accO);
                accO = MFMA32(aQ2, ld8B(&sSt[buf][l31][32 + 8*hi]), accO);
                accO = MFMA32(aQ3, ld8B(&sSt[buf][l31][48 + 8*hi]), accO);
            }
            // qz = q_t . ksum_prev (VALU dot over this lane's d-half)
            float qz = 0.0f;
            {
                const bf16x8 ks0 = ld16B(&sKSbf[ 0 + 8*hi]);
                const bf16x8 ks1 = ld16B(&sKSbf[16 + 8*hi]);
                const bf16x8 ks2 = ld16B(&sKSbf[32 + 8*hi]);
                const bf16x8 ks3 = ld16B(&sKSbf[48 + 8*hi]);
                #pragma unroll
                for (int j = 0; j < 8; ++j) {
                    qz += bf2f(aQ0[j]) * bf2f(ks0[j]);
                    qz += bf2f(aQ1[j]) * bf2f(ks1[j]);
                    qz += bf2f(aQ2[j]) * bf2f(ks2[j]);
                    qz += bf2f(aQ3[j]) * bf2f(ks3[j]);
                }
            }
            zl = halfswap_add(rs + qz);
        } else if (w < 10) {
            // -------- off-diagonal tile (pg,pc): P^T + partial PV --------
            f32x16 accP;
            #pragma unroll
            for (int i = 0; i < 16; ++i) accP[i] = 0.0f;
            #pragma unroll
            for (int kk = 0; kk < 4; ++kk)
                accP = MFMA32(ld16B(&sK[32*pg + l31][16*kk + 8*hi]),
                              ld16B(&sQ[32*pc + l31][16*kk + 8*hi]), accP);
            float rs = 0.0f;
            #pragma unroll
            for (int r = 0; r < 16; ++r) rs += accP[r];
            const float zp = halfswap_add(rs);
            if (hi == 0) sZp[pidx][l31] = zp;
            const bf16x8 pa0 = make_pa(accP[0],accP[1],accP[2],accP[3],
                                       accP[4],accP[5],accP[6],accP[7]);
            const bf16x8 pa1 = make_pa(accP[8],accP[9],accP[10],accP[11],
                                       accP[12],accP[13],accP[14],accP[15]);
            f32x16 po;
            #pragma unroll
            for (int i = 0; i < 16; ++i) po[i] = 0.0f;
            po = MFMA32(pa0, ld8B(&sVt[cur][l31][32*pg +  0 + 8*hi]), po);
            po = MFMA32(pa1, ld8B(&sVt[cur][l31][32*pg + 16 + 8*hi]), po);
            #pragma unroll
            for (int rp = 0; rp < 8; ++rp) {
                float2 t; t.x = po[2*rp]; t.y = po[2*rp+1];
                *(float2*)&sOp[pidx][rp][2*l] = t;
            }
        } else if (w < 14) {
            // -------- state: S(dt) += K^T V over s-half kh --------
            #pragma unroll
            for (int kk = 0; kk < 4; ++kk) {
                const bf16x8 aK = ld8B(&sKt[32*dt + l31][64*kh + 16*kk + 8*hi]);
                const bf16x8 bV = ld8B(&sVt[cur][l31][64*kh + 16*kk + 8*hi]);
                accS = MFMA32(aK, bV, accS);
            }
        }
        __syncthreads();   // bar2

        // ================= phase C: merge + normalize + store =================
        if (w < 4) {
            const int c = w;
            const int p0 = (c == 1) ? 0 : (c == 2) ? 1 : 3;
            for (int i = 0; i < c; ++i) {
                const int pp = p0 + i;
                #pragma unroll
                for (int rp = 0; rp < 8; ++rp) {
                    const float2 t = *(const float2*)&sOp[pp][rp][2*l];
                    accO[2*rp]     += t.x;
                    accO[2*rp + 1] += t.y;
                }
                zl += sZp[pp][l31];
            }
            zl += EPSV;
            if (hi == 0) sZt[32*c + l31] = zl;
            asm volatile("s_waitcnt lgkmcnt(0)" ::: "memory");
            __builtin_amdgcn_sched_barrier(0);
            #pragma unroll
            for (int rg = 0; rg < 4; ++rg) {
                const f32x4v z4 = *(const f32x4v*)&sZt[32*c + 8*rg + 4*hi];
                #pragma unroll
                for (int rr = 0; rr < 4; ++rr) {
                    const int row = t0 + 32*c + rr + 8*rg + 4*hi;
                    ob[(size_t)row * 1024 + l31] =
                        accO[4*rg + rr] * __builtin_amdgcn_rcpf(z4[rr]);
                }
            }
        }
        // no end barrier: bar1(t+1) fences all cross-phase reuse (audited R5).
    }
}

extern "C" void kernel_launch(void* const* d_in, const int* in_sizes, int n_in,
                              void* d_out, int out_size, void* d_ws, size_t ws_size,
                              hipStream_t stream) {
    const float* q = (const float*)d_in[0];
    const float* k = (const float*)d_in[1];
    const float* v = (const float*)d_in[2];
    float* o = (float*)d_out;
    dim3 grid(NBATCH * NHEAD * 2);   // 128 (n,h) x 2 m-halves = 256 blocks (1/CU)
    linattn_mfma6<<<grid, NTHREADS, 0, stream>>>(q, k, v, o);
}

// Round 8
// 119.766 us; speedup vs baseline: 1.0853x; 1.0340x over previous
//
#include <hip/hip_runtime.h>
#include <math.h>

#define NBATCH 8
#define SEQL   2048
#define NHEAD  16
#define DDIM   64
#define CHK    128
#define NCHUNK (SEQL / CHK)
#define MH     32
#define NTHREADS 1024
#define EPSV   1e-6f
#define QSTR   72      // sQ/sK row stride (ushort): 144B, 16B-aligned
#define TSTR   132     // sKt/sVt row stride: 264B, 8B-aligned
#define SSTR   68      // sSt row stride: 136B, 8B-aligned

typedef float  f32x16 __attribute__((ext_vector_type(16)));
typedef float  f32x4v __attribute__((ext_vector_type(4)));
typedef short  bf16x8 __attribute__((ext_vector_type(8)));

#define MFMA32(a,b,c) __builtin_amdgcn_mfma_f32_32x32x16_bf16((a),(b),(c),0,0,0)

__device__ __forceinline__ float phi(float x) { return x > 0.0f ? x + 1.0f : __expf(x); }

__device__ __forceinline__ unsigned int cvt_pk(float lo, float hi) {
    unsigned int r;
    asm("v_cvt_pk_bf16_f32 %0, %1, %2" : "=v"(r) : "v"(lo), "v"(hi));
    return r;
}
__device__ __forceinline__ ushort f2bf(float x) {
    union { float f; unsigned int i; } t; t.f = x;
    unsigned int r = t.i + 0x7fffu + ((t.i >> 16) & 1u);
    return (ushort)(r >> 16);
}
__device__ __forceinline__ float bf2f(short u) {
    union { unsigned int i; float f; } t;
    t.i = ((unsigned int)(unsigned short)u) << 16;
    return t.f;
}
__device__ __forceinline__ bf16x8 ld16B(const ushort* p) { return *reinterpret_cast<const bf16x8*>(p); }
__device__ __forceinline__ bf16x8 ld8B(const ushort* p) {
    union { bf16x8 v; uint2 u[2]; } x;
    x.u[0] = *(const uint2*)p;
    x.u[1] = *(const uint2*)(p + 4);
    return x.v;
}
__device__ __forceinline__ void pl32swap(unsigned int &a, unsigned int &b) {
    asm volatile("v_permlane32_swap_b32 %0, %1" : "+v"(a), "+v"(b));
}
__device__ __forceinline__ float halfswap_add(float x) {
    unsigned int a = __float_as_uint(x), b = a;
    pl32swap(a, b);
    return __uint_as_float(a) + __uint_as_float(b);
}
// P^T D-regs (s=crow(r,hi), t=l&31) -> PV A-fragment (row t, k slice). Verified R5.
__device__ __forceinline__ bf16x8 make_pa(float p0,float p1,float p2,float p3,
                                          float p4,float p5,float p6,float p7) {
    unsigned int a0 = cvt_pk(p0,p1), b0 = cvt_pk(p4,p5);
    unsigned int a1 = cvt_pk(p2,p3), b1 = cvt_pk(p6,p7);
    pl32swap(a0,b0); pl32swap(a1,b1);
    union { bf16x8 v; unsigned int u[4]; } x;
    x.u[0]=a0; x.u[1]=a1; x.u[2]=b0; x.u[3]=b1;
    return x.v;
}

__global__ __launch_bounds__(NTHREADS)
__attribute__((amdgpu_waves_per_eu(4, 4)))
void linattn_mfma6(const float* __restrict__ qg, const float* __restrict__ kg,
                   const float* __restrict__ vg, float* __restrict__ og) {
    __shared__ __align__(16) ushort sQ[CHK][QSTR];     // phi(Q) [t][d]
    __shared__ __align__(16) ushort sK[CHK][QSTR];     // phi(K) [s][d]
    __shared__ __align__(16) ushort sKt[DDIM][TSTR];   // phi(K)^T [d][s]
    __shared__ __align__(16) ushort sVt[2][MH][TSTR];  // V^T [pp][m][s]
    __shared__ __align__(16) ushort sSt[2][MH][SSTR];  // S^T snapshot halves [kh][m][d]
    __shared__ __align__(16) float  sOp[6][8][CHK];    // off-diag PV partial dumps
    __shared__ float sZp[6][32];                       // off-diag rowsum partials
    __shared__ float sZt[CHK];                         // final z per row
    __shared__ float sKsW[2][16][64];                  // per-wave k colsum partials
    __shared__ float sKS[64];                          // running ksum (f32)
    __shared__ __align__(16) ushort sKSbf[64];         // ksum bf16 row

    const int tid = threadIdx.x;
    const int w   = tid >> 6;
    const int l   = tid & 63;
    const int l31 = l & 31;
    const int hi  = l >> 5;

    const int bid   = blockIdx.x;
    const int nh    = bid & 127;       // b, b+128 share (n,h) -> same XCD slot
    const int mhalf = bid >> 7;
    const int n  = nh >> 4;
    const int hh = nh & 15;

    const size_t base0 = ((size_t)n * SEQL * NHEAD + hh) * DDIM;
    const float* qb = qg + base0;
    const float* kb = kg + base0;
    const float* vb = vg + base0 + (size_t)mhalf * MH;
    float*       ob = og + base0 + (size_t)mhalf * MH;

    // roles: w0-3 diag strips, 4-9 off-diag tiles, 10-13 state (dt,kh), 14 ksum
    const int pidx = w - 4;
    const int pc = (pidx < 1) ? 1 : (pidx < 3) ? 2 : 3;
    const int pg = pidx - ((pc == 1) ? 0 : (pc == 2) ? 1 : 3);
    const int dt = (w - 10) >> 1;
    const int kh = (w - 10) & 1;

    // staging geometry
    const int r2 = tid >> 4;           // 0..63 -> rows 2r2, 2r2+1
    const int x4 = (tid & 15) << 2;
    const int tv  = tid - 512;
    const int sp2 = (tv >> 3) << 1;
    const int vm4 = (tv & 7) << 2;

    float4 qrA, qrB, krA, krB, vrA, vrB;
    qrA = *(const float4*)(qb + (size_t)(2*r2    ) * 1024 + x4);
    qrB = *(const float4*)(qb + (size_t)(2*r2 + 1) * 1024 + x4);
    krA = *(const float4*)(kb + (size_t)(2*r2    ) * 1024 + x4);
    krB = *(const float4*)(kb + (size_t)(2*r2 + 1) * 1024 + x4);
    if (w >= 8) {
        vrA = *(const float4*)(vb + (size_t)(sp2    ) * 1024 + vm4);
        vrB = *(const float4*)(vb + (size_t)(sp2 + 1) * 1024 + vm4);
    }

    if (w == 14) sKS[l] = 0.0f;

    f32x16 accS;
    #pragma unroll
    for (int i = 0; i < 16; ++i) accS[i] = 0.0f;

    for (int tc = 0; tc < NCHUNK; ++tc) {
        const int t0 = tc * CHK;
        const int cur = tc & 1, prv = cur ^ 1;

        // ================= phase A: ksum commit + stage =================
        if (w == 14) {
            float s = sKS[l];
            if (tc > 0) {
                #pragma unroll
                for (int ww = 0; ww < 16; ++ww) s += sKsW[prv][ww][l];
                sKS[l] = s;
            }
            sKSbf[l] = f2bf(s);
        }
        {
            const float q0x=phi(qrA.x), q0y=phi(qrA.y), q0z=phi(qrA.z), q0w=phi(qrA.w);
            const float q1x=phi(qrB.x), q1y=phi(qrB.y), q1z=phi(qrB.z), q1w=phi(qrB.w);
            uint2 u;
            u.x = cvt_pk(q0x,q0y); u.y = cvt_pk(q0z,q0w);
            *(uint2*)&sQ[2*r2][x4] = u;
            u.x = cvt_pk(q1x,q1y); u.y = cvt_pk(q1z,q1w);
            *(uint2*)&sQ[2*r2+1][x4] = u;

            const float k0x=phi(krA.x), k0y=phi(krA.y), k0z=phi(krA.z), k0w=phi(krA.w);
            const float k1x=phi(krB.x), k1y=phi(krB.y), k1z=phi(krB.z), k1w=phi(krB.w);
            u.x = cvt_pk(k0x,k0y); u.y = cvt_pk(k0z,k0w);
            *(uint2*)&sK[2*r2][x4] = u;
            u.x = cvt_pk(k1x,k1y); u.y = cvt_pk(k1z,k1w);
            *(uint2*)&sK[2*r2+1][x4] = u;

            *(unsigned int*)&sKt[x4+0][2*r2] = cvt_pk(k0x, k1x);
            *(unsigned int*)&sKt[x4+1][2*r2] = cvt_pk(k0y, k1y);
            *(unsigned int*)&sKt[x4+2][2*r2] = cvt_pk(k0z, k1z);
            *(unsigned int*)&sKt[x4+3][2*r2] = cvt_pk(k0w, k1w);

            float kp0 = k0x + k1x, kp1 = k0y + k1y, kp2 = k0z + k1z, kp3 = k0w + k1w;
            kp0 += __shfl_xor(kp0, 16); kp0 += __shfl_xor(kp0, 32);
            kp1 += __shfl_xor(kp1, 16); kp1 += __shfl_xor(kp1, 32);
            kp2 += __shfl_xor(kp2, 16); kp2 += __shfl_xor(kp2, 32);
            kp3 += __shfl_xor(kp3, 16); kp3 += __shfl_xor(kp3, 32);
            if (l < 16) {
                float4 kp = {kp0, kp1, kp2, kp3};
                *(float4*)&sKsW[cur][w][4*l] = kp;
            }
        }
        if (w >= 8) {
            *(unsigned int*)&sVt[cur][vm4+0][sp2] = cvt_pk(vrA.x, vrB.x);
            *(unsigned int*)&sVt[cur][vm4+1][sp2] = cvt_pk(vrA.y, vrB.y);
            *(unsigned int*)&sVt[cur][vm4+2][sp2] = cvt_pk(vrA.z, vrB.z);
            *(unsigned int*)&sVt[cur][vm4+3][sp2] = cvt_pk(vrA.w, vrB.w);
        }
        if (w >= 10 && w < 14) {       // snapshot S^T (this wave's (dt,kh) tile)
            ushort* st = &sSt[kh][l31][32*dt];
            #pragma unroll
            for (int rg = 0; rg < 4; ++rg) {
                uint2 s2;
                s2.x = cvt_pk(accS[4*rg+0], accS[4*rg+1]);
                s2.y = cvt_pk(accS[4*rg+2], accS[4*rg+3]);
                *(uint2*)(st + 8*rg + 4*hi) = s2;
            }
        }
        __syncthreads();   // bar1

        // ================= phase B: prefetch + all matmuls =================
        if (tc + 1 < NCHUNK) {
            const int t1 = t0 + CHK;
            qrA = *(const float4*)(qb + (size_t)(t1 + 2*r2    ) * 1024 + x4);
            qrB = *(const float4*)(qb + (size_t)(t1 + 2*r2 + 1) * 1024 + x4);
            krA = *(const float4*)(kb + (size_t)(t1 + 2*r2    ) * 1024 + x4);
            krB = *(const float4*)(kb + (size_t)(t1 + 2*r2 + 1) * 1024 + x4);
            if (w >= 8) {
                vrA = *(const float4*)(vb + (size_t)(t1 + sp2    ) * 1024 + vm4);
                vrB = *(const float4*)(vb + (size_t)(t1 + sp2 + 1) * 1024 + vm4);
            }
        }

        f32x16 accO;
        float zl = 0.0f;

        if (w < 4) {
            // -------- diagonal strip c=w: QK^T(c,c) + PV + QS + qz --------
            const int c = w;
            const bf16x8 aQ0 = ld16B(&sQ[32*c + l31][ 0 + 8*hi]);
            const bf16x8 aQ1 = ld16B(&sQ[32*c + l31][16 + 8*hi]);
            const bf16x8 aQ2 = ld16B(&sQ[32*c + l31][32 + 8*hi]);
            const bf16x8 aQ3 = ld16B(&sQ[32*c + l31][48 + 8*hi]);

            f32x16 accP;
            #pragma unroll
            for (int i = 0; i < 16; ++i) accP[i] = 0.0f;
            accP = MFMA32(ld16B(&sK[32*c + l31][ 0 + 8*hi]), aQ0, accP);
            accP = MFMA32(ld16B(&sK[32*c + l31][16 + 8*hi]), aQ1, accP);
            accP = MFMA32(ld16B(&sK[32*c + l31][32 + 8*hi]), aQ2, accP);
            accP = MFMA32(ld16B(&sK[32*c + l31][48 + 8*hi]), aQ3, accP);
            // causal mask (s<=t) + rowsum, all in D-registers
            float rs = 0.0f;
            #pragma unroll
            for (int r = 0; r < 16; ++r) {
                const int srow = (r & 3) + 8 * (r >> 2) + 4 * hi;
                const float pv = (srow <= l31) ? accP[r] : 0.0f;
                accP[r] = pv;
                rs += pv;
            }
            const bf16x8 pa0 = make_pa(accP[0],accP[1],accP[2],accP[3],
                                       accP[4],accP[5],accP[6],accP[7]);
            const bf16x8 pa1 = make_pa(accP[8],accP[9],accP[10],accP[11],
                                       accP[12],accP[13],accP[14],accP[15]);
            #pragma unroll
            for (int i = 0; i < 16; ++i) accO[i] = 0.0f;
            accO = MFMA32(pa0, ld8B(&sVt[cur][l31][32*c +  0 + 8*hi]), accO);
            accO = MFMA32(pa1, ld8B(&sVt[cur][l31][32*c + 16 + 8*hi]), accO);
            #pragma unroll
            for (int buf = 0; buf < 2; ++buf) {
                accO = MFMA32(aQ0, ld8B(&sSt[buf][l31][ 0 + 8*hi]), accO);
                accO = MFMA32(aQ1, ld8B(&sSt[buf][l31][16 + 8*hi]), accO);
                accO = MFMA32(aQ2, ld8B(&sSt[buf][l31][32 + 8*hi]), accO);
                accO = MFMA32(aQ3, ld8B(&sSt[buf][l31][48 + 8*hi]), accO);
            }
            // qz = q_t . ksum_prev (VALU dot over this lane's d-half)
            float qz = 0.0f;
            {
                const bf16x8 ks0 = ld16B(&sKSbf[ 0 + 8*hi]);
                const bf16x8 ks1 = ld16B(&sKSbf[16 + 8*hi]);
                const bf16x8 ks2 = ld16B(&sKSbf[32 + 8*hi]);
                const bf16x8 ks3 = ld16B(&sKSbf[48 + 8*hi]);
                #pragma unroll
                for (int j = 0; j < 8; ++j) {
                    qz += bf2f(aQ0[j]) * bf2f(ks0[j]);
                    qz += bf2f(aQ1[j]) * bf2f(ks1[j]);
                    qz += bf2f(aQ2[j]) * bf2f(ks2[j]);
                    qz += bf2f(aQ3[j]) * bf2f(ks3[j]);
                }
            }
            zl = halfswap_add(rs + qz);
        } else if (w < 10) {
            // -------- off-diagonal tile (pg,pc): P^T + partial PV --------
            f32x16 accP;
            #pragma unroll
            for (int i = 0; i < 16; ++i) accP[i] = 0.0f;
            #pragma unroll
            for (int kk = 0; kk < 4; ++kk)
                accP = MFMA32(ld16B(&sK[32*pg + l31][16*kk + 8*hi]),
                              ld16B(&sQ[32*pc + l31][16*kk + 8*hi]), accP);
            float rs = 0.0f;
            #pragma unroll
            for (int r = 0; r < 16; ++r) rs += accP[r];
            const float zp = halfswap_add(rs);
            if (hi == 0) sZp[pidx][l31] = zp;
            const bf16x8 pa0 = make_pa(accP[0],accP[1],accP[2],accP[3],
                                       accP[4],accP[5],accP[6],accP[7]);
            const bf16x8 pa1 = make_pa(accP[8],accP[9],accP[10],accP[11],
                                       accP[12],accP[13],accP[14],accP[15]);
            f32x16 po;
            #pragma unroll
            for (int i = 0; i < 16; ++i) po[i] = 0.0f;
            po = MFMA32(pa0, ld8B(&sVt[cur][l31][32*pg +  0 + 8*hi]), po);
            po = MFMA32(pa1, ld8B(&sVt[cur][l31][32*pg + 16 + 8*hi]), po);
            #pragma unroll
            for (int rp = 0; rp < 8; ++rp) {
                float2 t; t.x = po[2*rp]; t.y = po[2*rp+1];
                *(float2*)&sOp[pidx][rp][2*l] = t;
            }
        } else if (w < 14) {
            // -------- state: S(dt) += K^T V over s-half kh --------
            #pragma unroll
            for (int kk = 0; kk < 4; ++kk) {
                const bf16x8 aK = ld8B(&sKt[32*dt + l31][64*kh + 16*kk + 8*hi]);
                const bf16x8 bV = ld8B(&sVt[cur][l31][64*kh + 16*kk + 8*hi]);
                accS = MFMA32(aK, bV, accS);
            }
        }
        __syncthreads();   // bar2

        // ================= phase C: merge + normalize + store =================
        if (w < 4) {
            const int c = w;
            const int p0 = (c == 1) ? 0 : (c == 2) ? 1 : 3;
            for (int i = 0; i < c; ++i) {
                const int pp = p0 + i;
                #pragma unroll
                for (int rp = 0; rp < 8; ++rp) {
                    const float2 t = *(const float2*)&sOp[pp][rp][2*l];
                    accO[2*rp]     += t.x;
                    accO[2*rp + 1] += t.y;
                }
                zl += sZp[pp][l31];
            }
            zl += EPSV;
            if (hi == 0) sZt[32*c + l31] = zl;
            asm volatile("s_waitcnt lgkmcnt(0)" ::: "memory");
            __builtin_amdgcn_sched_barrier(0);
            #pragma unroll
            for (int rg = 0; rg < 4; ++rg) {
                const f32x4v z4 = *(const f32x4v*)&sZt[32*c + 8*rg + 4*hi];
                #pragma unroll
                for (int rr = 0; rr < 4; ++rr) {
                    const int row = t0 + 32*c + rr + 8*rg + 4*hi;
                    ob[(size_t)row * 1024 + l31] =
                        accO[4*rg + rr] * __builtin_amdgcn_rcpf(z4[rr]);
                }
            }
        }
        // no end barrier: bar1(t+1) fences all cross-phase reuse (audited R5).
    }
}

extern "C" void kernel_launch(void* const* d_in, const int* in_sizes, int n_in,
                              void* d_out, int out_size, void* d_ws, size_t ws_size,
                              hipStream_t stream) {
    const float* q = (const float*)d_in[0];
    const float* k = (const float*)d_in[1];
    const float* v = (const float*)d_in[2];
    float* o = (float*)d_out;
    dim3 grid(NBATCH * NHEAD * 2);   // 128 (n,h) x 2 m-halves = 256 blocks (1/CU)
    linattn_mfma6<<<grid, NTHREADS, 0, stream>>>(q, k, v, o);
}